// Round 5
// baseline (216.096 us; speedup 1.0000x reference)
//
#include <hip/hip_runtime.h>
#include <hip/hip_bf16.h>

#define IN_CH 256
#define HC    128   // HEADS * C
#define HEADS 4
#define CPH   32    // channels per head
#define NEG_SLOPE 0.2f
#define BM 64
#define BK 16

// ---------- K_gemm v5: xp = x @ W (M=n, N=128, K=256), fused att-dot epilogue ----------
// LDS-issue-bound analysis: ds_read_b128 ~12cy each, so minimize LDS instrs per FMA.
// 128 threads (2 waves), BM=64, per-thread 8 rows x 8 cols: per kk
// 2xb128 (A) + 2xb128 (B) feed 64 FMAs -> 1.0 B/FMA (was 2.5).
// B fragment = cols [tx*4,+4) U [64+tx*4,+4): 16B lane stride -> 2-way banks = free.
// A fragment As[kk][ty*8]: 8 addrs broadcast to 16 lanes, <=2 addrs/bank = free.
// Double-buffered LDS + register prefetch. Epilogue: attdots via LDS, coalesced dump.
__global__ __launch_bounds__(128) void k_gemm(const float* __restrict__ x,
                                              const float* __restrict__ W,
                                              const float* __restrict__ att_src,
                                              const float* __restrict__ att_dst,
                                              float* __restrict__ xp,
                                              float* __restrict__ asrc,
                                              float* __restrict__ adst,
                                              int* __restrict__ cnt, int n) {
    __shared__ float As[2][BK][68];
    __shared__ float Bs[2][BK][128];
    const int tid = threadIdx.x;
    const int m0 = blockIdx.x * BM;
    const int tx = tid & 15;       // column group
    const int ty = tid >> 4;       // 0..7 -> rows ty*8 .. ty*8+7
    const int cA = tx * 4;         // first 4 cols; second 4 are 64+cA

    // loader roles (128 threads)
    const int arow = tid >> 1;          // 0..63 (x row in tile)
    const int ak   = (tid & 1) * 8;     // k offset: 0 or 8 (two float4 each)
    const int bcol = (tid & 31) * 4;    // W col (float4)
    const int brow = tid >> 5;          // W row 0..3 (+4j)

    float acc[8][8];
#pragma unroll
    for (int i = 0; i < 8; ++i)
#pragma unroll
        for (int j = 0; j < 8; ++j) acc[i][j] = 0.f;

    const bool aval = (m0 + arow) < n;
    const float* xrow = x + (size_t)(m0 + arow) * IN_CH + ak;

    float4 xa0 = make_float4(0.f, 0.f, 0.f, 0.f);
    float4 xa1 = make_float4(0.f, 0.f, 0.f, 0.f);
    if (aval) {
        xa0 = *(const float4*)(xrow);
        xa1 = *(const float4*)(xrow + 4);
    }
    float4 wb[4];
#pragma unroll
    for (int j = 0; j < 4; ++j)
        wb[j] = *(const float4*)(W + (size_t)(brow + 4 * j) * HC + bcol);

    As[0][ak + 0][arow] = xa0.x;
    As[0][ak + 1][arow] = xa0.y;
    As[0][ak + 2][arow] = xa0.z;
    As[0][ak + 3][arow] = xa0.w;
    As[0][ak + 4][arow] = xa1.x;
    As[0][ak + 5][arow] = xa1.y;
    As[0][ak + 6][arow] = xa1.z;
    As[0][ak + 7][arow] = xa1.w;
#pragma unroll
    for (int j = 0; j < 4; ++j)
        *(float4*)(&Bs[0][brow + 4 * j][bcol]) = wb[j];
    __syncthreads();

    const int NCH = IN_CH / BK;  // 16
    for (int c = 0; c < NCH; ++c) {
        const int cur = c & 1;
        if (c + 1 < NCH) {  // prefetch next chunk into registers
            const int k0 = (c + 1) * BK;
            if (aval) {
                xa0 = *(const float4*)(xrow + k0);
                xa1 = *(const float4*)(xrow + k0 + 4);
            }
#pragma unroll
            for (int j = 0; j < 4; ++j)
                wb[j] = *(const float4*)(W + (size_t)(k0 + brow + 4 * j) * HC + bcol);
        }
#pragma unroll
        for (int kk = 0; kk < BK; ++kk) {
            float a[8], b[8];
            *(float4*)(a)     = *(const float4*)(&As[cur][kk][ty * 8]);
            *(float4*)(a + 4) = *(const float4*)(&As[cur][kk][ty * 8 + 4]);
            *(float4*)(b)     = *(const float4*)(&Bs[cur][kk][cA]);
            *(float4*)(b + 4) = *(const float4*)(&Bs[cur][kk][64 + cA]);
#pragma unroll
            for (int i = 0; i < 8; ++i)
#pragma unroll
                for (int j = 0; j < 8; ++j) acc[i][j] += a[i] * b[j];
        }
        if (c + 1 < NCH) {
            __syncthreads();  // everyone done reading the buffer we overwrite
            const int nxt = cur ^ 1;
            As[nxt][ak + 0][arow] = xa0.x;
            As[nxt][ak + 1][arow] = xa0.y;
            As[nxt][ak + 2][arow] = xa0.z;
            As[nxt][ak + 3][arow] = xa0.w;
            As[nxt][ak + 4][arow] = xa1.x;
            As[nxt][ak + 5][arow] = xa1.y;
            As[nxt][ak + 6][arow] = xa1.z;
            As[nxt][ak + 7][arow] = xa1.w;
#pragma unroll
            for (int j = 0; j < 4; ++j)
                *(float4*)(&Bs[nxt][brow + 4 * j][bcol]) = wb[j];
            __syncthreads();  // writes visible before next compute
        }
    }

    // ---- epilogue: xp write + fused attention dots (coalesced via LDS staging) ----
    __syncthreads();
    float* sE = (float*)As;  // reuse: 512 floats needed

    float4 vsl = *(const float4*)(att_src + cA);
    float4 vsh = *(const float4*)(att_src + 64 + cA);
    float4 vdl = *(const float4*)(att_dst + cA);
    float4 vdh = *(const float4*)(att_dst + 64 + cA);
#pragma unroll
    for (int i = 0; i < 8; ++i) {
        const int r = ty * 8 + i;       // local row 0..63
        const int gr = m0 + r;
        float sl = acc[i][0] * vsl.x + acc[i][1] * vsl.y + acc[i][2] * vsl.z + acc[i][3] * vsl.w;
        float sh = acc[i][4] * vsh.x + acc[i][5] * vsh.y + acc[i][6] * vsh.z + acc[i][7] * vsh.w;
        float dl = acc[i][0] * vdl.x + acc[i][1] * vdl.y + acc[i][2] * vdl.z + acc[i][3] * vdl.w;
        float dh = acc[i][4] * vdh.x + acc[i][5] * vdh.y + acc[i][6] * vdh.z + acc[i][7] * vdh.w;
        // reduce over the 8 lanes sharing a head (tx bits 0..2)
        sl += __shfl_xor(sl, 1, 64); sl += __shfl_xor(sl, 2, 64); sl += __shfl_xor(sl, 4, 64);
        sh += __shfl_xor(sh, 1, 64); sh += __shfl_xor(sh, 2, 64); sh += __shfl_xor(sh, 4, 64);
        dl += __shfl_xor(dl, 1, 64); dl += __shfl_xor(dl, 2, 64); dl += __shfl_xor(dl, 4, 64);
        dh += __shfl_xor(dh, 1, 64); dh += __shfl_xor(dh, 2, 64); dh += __shfl_xor(dh, 4, 64);
        if ((tx & 7) == 0) {
            const int hl = tx >> 3;       // 0 or 1
            sE[r * 4 + hl]           = sl;
            sE[r * 4 + 2 + hl]       = sh;
            sE[256 + r * 4 + hl]     = dl;
            sE[256 + r * 4 + 2 + hl] = dh;
        }
        if (gr < n) {
            *(float4*)(xp + (size_t)gr * HC + cA)      = *(float4*)(&acc[i][0]);
            *(float4*)(xp + (size_t)gr * HC + 64 + cA) = *(float4*)(&acc[i][4]);
        }
    }
    __syncthreads();
    if (tid < 64) {
        if (m0 + tid < n) {
            ((float4*)asrc)[m0 + tid] = ((const float4*)sE)[tid];
            cnt[m0 + tid] = 1;
        }
    } else {
        const int r = tid - 64;
        if (m0 + r < n) ((float4*)adst)[m0 + r] = ((const float4*)sE)[64 + r];
    }
}

// ---------- K_count ----------
__global__ void k_count(const int* __restrict__ ei, int* __restrict__ cnt, int E) {
    int e = blockIdx.x * blockDim.x + threadIdx.x;
    if (e >= E) return;
    atomicAdd(cnt + ei[E + e], 1);
}

// ---------- hierarchical scan: chunk=1024 ----------
// scan1: per-chunk reduce -> bsum[b]
__global__ __launch_bounds__(256) void k_scan1(const int* __restrict__ cnt,
                                               int* __restrict__ bsum, int n) {
    __shared__ int sm[256];
    int b = blockIdx.x, t = threadIdx.x;
    int base = b << 10;
    int s = 0;
#pragma unroll
    for (int j = 0; j < 4; ++j) {
        int i = base + t + j * 256;
        if (i < n) s += cnt[i];
    }
    sm[t] = s;
    __syncthreads();
    for (int d = 128; d > 0; d >>= 1) {
        if (t < d) sm[t] += sm[t + d];
        __syncthreads();
    }
    if (t == 0) bsum[b] = sm[0];
}

// scan2: exclusive scan of bsum (nb <= 1024); also offs[n] = total (known statically)
__global__ __launch_bounds__(1024) void k_scan2(int* __restrict__ bsum,
                                                int* __restrict__ offs,
                                                int nb, int n, int total) {
    __shared__ int sm[1024];
    int t = threadIdx.x;
    int orig = (t < nb) ? bsum[t] : 0;
    sm[t] = orig;
    __syncthreads();
    for (int d = 1; d < 1024; d <<= 1) {
        int v = (t >= d) ? sm[t - d] : 0;
        __syncthreads();
        sm[t] += v;
        __syncthreads();
    }
    if (t < nb) bsum[t] = sm[t] - orig;  // exclusive base per chunk
    if (t == 0) offs[n] = total;
}

// scan3: per-chunk exclusive scan (4 elems/thread) + chunk base -> offs, cursor
__global__ __launch_bounds__(256) void k_scan3(const int* __restrict__ cnt,
                                               const int* __restrict__ bsum,
                                               int* __restrict__ offs,
                                               int* __restrict__ cursor, int n) {
    __shared__ int sm[256];
    int b = blockIdx.x, t = threadIdx.x;
    int base = (b << 10) + t * 4;
    int c[4];
    int s = 0;
#pragma unroll
    for (int j = 0; j < 4; ++j) {
        int i = base + j;
        c[j] = (i < n) ? cnt[i] : 0;
        s += c[j];
    }
    sm[t] = s;
    __syncthreads();
    for (int d = 1; d < 256; d <<= 1) {
        int v = (t >= d) ? sm[t - d] : 0;
        __syncthreads();
        sm[t] += v;
        __syncthreads();
    }
    int excl = bsum[b] + ((t == 0) ? 0 : sm[t - 1]);
#pragma unroll
    for (int j = 0; j < 4; ++j) {
        int i = base + j;
        if (i < n) { offs[i] = excl; cursor[i] = excl; }
        excl += c[j];
    }
}

// ---------- K_fill ----------
__global__ void k_fill(const int* __restrict__ ei, int* __restrict__ cursor,
                       int* __restrict__ srcs, int E, int n) {
    int e = blockIdx.x * blockDim.x + threadIdx.x;
    if (e >= E + n) return;
    int s, d;
    if (e < E) { s = ei[e]; d = ei[E + e]; } else { s = d = e - E; }
    int pos = atomicAdd(cursor + d, 1);
    srcs[pos] = s;
}

// ---------- K_gat: one wave per dst node ----------
// pass 1: softmax stats (srcs staged via LDS).
// pass 2: 4 quarter-waves process 4 edges in parallel (8 in flight),
//         each lane owns 8 channels (2 x float4) -> coalesced 512B row/quarter.
__global__ __launch_bounds__(256) void k_gat(const int* __restrict__ offs,
                                             const int* __restrict__ srcs,
                                             const float* __restrict__ asrc,
                                             const float* __restrict__ adst,
                                             const float* __restrict__ xp,
                                             const float* __restrict__ bias,
                                             float* __restrict__ out, int n) {
    __shared__ int sS[4][128];
    const int wid = threadIdx.x >> 6;
    const int wave = blockIdx.x * 4 + wid;
    if (wave >= n) return;
    const int lane = threadIdx.x & 63;
    const int d = wave;
    const int start = offs[d], end = offs[d + 1];
    const int deg = end - start;

    const int h = lane & 3;
    const float ad_h = adst[(size_t)d * 4 + h];
    float m = -1e30f, Z = 0.f;

    // ---- pass 1: online softmax stats over chunks of <=128 edges ----
    for (int c0 = start; c0 < end; c0 += 128) {
        const int cn = min(128, end - c0);
        if (c0 + lane < end)      sS[wid][lane]      = srcs[c0 + lane];
        if (c0 + 64 + lane < end) sS[wid][64 + lane] = srcs[c0 + 64 + lane];
        asm volatile("s_waitcnt lgkmcnt(0)" ::: "memory");  // intra-wave LDS visibility
        for (int i = (lane >> 2); i < cn; i += 16) {
            int s = sS[wid][i];
            float t = asrc[(size_t)s * 4 + h] + ad_h;
            t = t > 0.f ? t : NEG_SLOPE * t;
            float nm = fmaxf(m, t);
            Z = Z * __expf(m - nm) + __expf(t - nm);
            m = nm;
        }
    }
#pragma unroll
    for (int off = 4; off < 64; off <<= 1) {
        float om = __shfl_xor(m, off, 64);
        float oZ = __shfl_xor(Z, off, 64);
        float nm = fmaxf(m, om);
        Z = Z * __expf(m - nm) + oZ * __expf(om - nm);
        m = nm;
    }

    // ---- pass 2 ----
    const int cl = lane & 15;   // channel lane: channels [cl*8, cl*8+8)
    const int eg = lane >> 4;   // edge slot (4 edges in parallel)
    const int hh = cl >> 2;     // head owning this channel slice
    const float m2  = __shfl(m, hh, 64);
    const float rZ  = 1.0f / __shfl(Z, hh, 64);
    const float ad2 = __shfl(ad_h, hh, 64);

    float4 a0 = make_float4(0.f, 0.f, 0.f, 0.f);
    float4 a1 = make_float4(0.f, 0.f, 0.f, 0.f);

    for (int c0 = start; c0 < end; c0 += 128) {
        const int cn = min(128, end - c0);
        if (deg > 128) {  // multi-chunk fallback: re-stage this chunk
            if (c0 + lane < end)      sS[wid][lane]      = srcs[c0 + lane];
            if (c0 + 64 + lane < end) sS[wid][64 + lane] = srcs[c0 + 64 + lane];
            asm volatile("s_waitcnt lgkmcnt(0)" ::: "memory");
        }
        const int full = cn & ~7;
        int i = 0;
        for (; i < full; i += 8) {  // 8 edges in flight, no guards
            int sa = sS[wid][i + eg];
            int sb = sS[wid][i + 4 + eg];
            float ta = asrc[(size_t)sa * 4 + hh] + ad2;
            float tb = asrc[(size_t)sb * 4 + hh] + ad2;
            const float4* xa = (const float4*)(xp + (size_t)sa * HC + cl * 8);
            const float4* xb = (const float4*)(xp + (size_t)sb * HC + cl * 8);
            float4 va0 = xa[0], va1 = xa[1];
            float4 vb0 = xb[0], vb1 = xb[1];
            ta = ta > 0.f ? ta : NEG_SLOPE * ta;
            tb = tb > 0.f ? tb : NEG_SLOPE * tb;
            float aa = __expf(ta - m2) * rZ;
            float ab = __expf(tb - m2) * rZ;
            a0.x += aa * va0.x; a0.y += aa * va0.y; a0.z += aa * va0.z; a0.w += aa * va0.w;
            a1.x += aa * va1.x; a1.y += aa * va1.y; a1.z += aa * va1.z; a1.w += aa * va1.w;
            a0.x += ab * vb0.x; a0.y += ab * vb0.y; a0.z += ab * vb0.z; a0.w += ab * vb0.w;
            a1.x += ab * vb1.x; a1.y += ab * vb1.y; a1.z += ab * vb1.z; a1.w += ab * vb1.w;
        }
        for (; i < cn; i += 4) {  // tail: exec-masked so no wasted row loads
            if (i + eg < cn) {
                int s = sS[wid][i + eg];
                float t = asrc[(size_t)s * 4 + hh] + ad2;
                const float4* xr = (const float4*)(xp + (size_t)s * HC + cl * 8);
                float4 v0 = xr[0], v1 = xr[1];
                t = t > 0.f ? t : NEG_SLOPE * t;
                float al = __expf(t - m2) * rZ;
                a0.x += al * v0.x; a0.y += al * v0.y; a0.z += al * v0.z; a0.w += al * v0.w;
                a1.x += al * v1.x; a1.y += al * v1.y; a1.z += al * v1.z; a1.w += al * v1.w;
            }
        }
    }

    // reduce across the 4 edge groups (lane bits 4 and 5)
#pragma unroll
    for (int off = 16; off < 64; off <<= 1) {
        a0.x += __shfl_xor(a0.x, off, 64); a0.y += __shfl_xor(a0.y, off, 64);
        a0.z += __shfl_xor(a0.z, off, 64); a0.w += __shfl_xor(a0.w, off, 64);
        a1.x += __shfl_xor(a1.x, off, 64); a1.y += __shfl_xor(a1.y, off, 64);
        a1.z += __shfl_xor(a1.z, off, 64); a1.w += __shfl_xor(a1.w, off, 64);
    }

    if (eg == 0) {
        const float4* bp = (const float4*)bias + cl * 2;
        float4 b0 = bp[0], b1 = bp[1];
        float4 o0, o1;
        o0.x = fmaxf(a0.x + b0.x, 0.f); o0.y = fmaxf(a0.y + b0.y, 0.f);
        o0.z = fmaxf(a0.z + b0.z, 0.f); o0.w = fmaxf(a0.w + b0.w, 0.f);
        o1.x = fmaxf(a1.x + b1.x, 0.f); o1.y = fmaxf(a1.y + b1.y, 0.f);
        o1.z = fmaxf(a1.z + b1.z, 0.f); o1.w = fmaxf(a1.w + b1.w, 0.f);
        float4* op = (float4*)(out + (size_t)d * HC) + cl * 2;
        op[0] = o0; op[1] = o1;
    }
}

extern "C" void kernel_launch(void* const* d_in, const int* in_sizes, int n_in,
                              void* d_out, int out_size, void* d_ws, size_t ws_size,
                              hipStream_t stream) {
    const float* x       = (const float*)d_in[0];
    const int*   ei      = (const int*)d_in[1];
    const float* W       = (const float*)d_in[3];
    const float* att_src = (const float*)d_in[4];
    const float* att_dst = (const float*)d_in[5];
    const float* bias    = (const float*)d_in[6];
    float* out = (float*)d_out;

    const int n = in_sizes[0] / IN_CH;   // 40000
    const int E = in_sizes[1] / 2;       // 640000
    const int EN = E + n;
    const int NB = (n + 1023) >> 10;     // scan chunks

    // workspace layout
    float* xp   = (float*)d_ws;                          // n*128 f32
    float* asrc = xp + (size_t)n * HC;                   // n*4
    float* adst = asrc + (size_t)n * HEADS;              // n*4
    int*   cnt    = (int*)(adst + (size_t)n * HEADS);    // n
    int*   offs   = cnt + n;                             // n+1
    int*   cursor = offs + n + 1;                        // n
    int*   bsum   = cursor + n;                          // NB
    int*   srcs   = bsum + 1024;                         // E+n

    k_gemm<<<dim3((n + BM - 1) / BM), 128, 0, stream>>>(x, W, att_src, att_dst, xp, asrc, adst, cnt, n);
    k_count<<<(E + 255) / 256, 256, 0, stream>>>(ei, cnt, E);
    k_scan1<<<NB, 256, 0, stream>>>(cnt, bsum, n);
    k_scan2<<<1, 1024, 0, stream>>>(bsum, offs, NB, n, EN);
    k_scan3<<<NB, 256, 0, stream>>>(cnt, bsum, offs, cursor, n);
    k_fill<<<(EN + 255) / 256, 256, 0, stream>>>(ei, cursor, srcs, E, n);
    k_gat<<<(n + 3) / 4, 256, 0, stream>>>(offs, srcs, asrc, adst, xp, bias, out, n);
}

// Round 6
// 180.144 us; speedup vs baseline: 1.1996x; 1.1996x over previous
//
#include <hip/hip_runtime.h>
#include <hip/hip_bf16.h>

#define IN_CH 256
#define HC    128   // HEADS * C
#define HEADS 4
#define CPH   32    // channels per head
#define NEG_SLOPE 0.2f
#define BM 160
#define BK 16

// ---------- K_gemm v6: xp = x @ W (M=n, N=128, K=256), fused att-dot epilogue ----------
// Model: LDS unit is per-CU (~12cy/b128). Minimize LDS reads per FMA *and* keep one
// balanced block per CU:
//   BM=160, 256 threads, per-thread 10 rows x 8 cols: 5 reads (2xb128+b64 A, 2xb128 B)
//   feed 80 FMAs. grid = 40000/160 = 250 blocks = 1/CU, single round, no tail.
// A rows live at stride-12 slots (48B) so 10-row fragments are 16B-aligned b128s and
// per-instruction bank-disjoint. B fragment = cols [tx*4,+4) U [64+tx*4,+4) (2-way = free).
// Double-buffered LDS + register prefetch. Epilogue: attdots via LDS, coalesced dump.
__global__ __launch_bounds__(256) void k_gemm(const float* __restrict__ x,
                                              const float* __restrict__ W,
                                              const float* __restrict__ att_src,
                                              const float* __restrict__ att_dst,
                                              float* __restrict__ xp,
                                              float* __restrict__ asrc,
                                              float* __restrict__ adst,
                                              int* __restrict__ cnt, int n) {
    __shared__ float As[2][BK][196];   // slot = (row/10)*12 + row%10  (192 used, pad 4)
    __shared__ float Bs[2][BK][128];
    const int tid = threadIdx.x;
    const int m0 = blockIdx.x * BM;
    const int tx = tid & 15;        // column group
    const int ty = tid >> 4;        // 0..15 -> rows ty*10 .. ty*10+9
    const int ty12 = ty * 12;       // LDS slot base of this row group
    const int cA = tx * 4;          // first 4 cols; second 4 are 64+cA

    // ---- loader roles ----
    // A: 1280 float2 (160 rows x 8 k-pairs); thread t takes kp=t&7, rows (t>>3)+32j
    const int kp  = tid & 7;
    const int kp2 = kp * 2;
    const int ar0 = tid >> 3;           // base row 0..31
    int aslot[5];
    const float* aptr[5];
    bool avalid[5];
#pragma unroll
    for (int j = 0; j < 5; ++j) {
        const int row = ar0 + 32 * j;
        aslot[j] = (row / 10) * 12 + row % 10;
        avalid[j] = (m0 + row) < n;
        aptr[j] = x + (size_t)(m0 + row) * IN_CH + kp * 2;
    }
    // B: brow 0..7 (+8), bcol
    const int brow = tid >> 5;
    const int bcol = (tid & 31) * 4;

    float acc[10][8];
#pragma unroll
    for (int i = 0; i < 10; ++i)
#pragma unroll
        for (int j = 0; j < 8; ++j) acc[i][j] = 0.f;

    float2 xa[5];
    float4 wb0, wb1;
#pragma unroll
    for (int j = 0; j < 5; ++j) {
        xa[j] = make_float2(0.f, 0.f);
        if (avalid[j]) xa[j] = *(const float2*)(aptr[j]);
    }
    wb0 = *(const float4*)(W + (size_t)brow * HC + bcol);
    wb1 = *(const float4*)(W + (size_t)(brow + 8) * HC + bcol);

#pragma unroll
    for (int j = 0; j < 5; ++j) {
        As[0][kp2][aslot[j]]     = xa[j].x;
        As[0][kp2 + 1][aslot[j]] = xa[j].y;
    }
    *(float4*)(&Bs[0][brow][bcol])     = wb0;
    *(float4*)(&Bs[0][brow + 8][bcol]) = wb1;
    __syncthreads();

    const int NCH = IN_CH / BK;  // 16
    for (int c = 0; c < NCH; ++c) {
        const int cur = c & 1;
        if (c + 1 < NCH) {  // prefetch next chunk into registers
            const int k0 = (c + 1) * BK;
#pragma unroll
            for (int j = 0; j < 5; ++j)
                if (avalid[j]) xa[j] = *(const float2*)(aptr[j] + k0);
            wb0 = *(const float4*)(W + (size_t)(k0 + brow) * HC + bcol);
            wb1 = *(const float4*)(W + (size_t)(k0 + brow + 8) * HC + bcol);
        }
#pragma unroll
        for (int kk = 0; kk < BK; ++kk) {
            float a[10], b[8];
            *(float4*)(a)     = *(const float4*)(&As[cur][kk][ty12]);
            *(float4*)(a + 4) = *(const float4*)(&As[cur][kk][ty12 + 4]);
            *(float2*)(a + 8) = *(const float2*)(&As[cur][kk][ty12 + 8]);
            *(float4*)(b)     = *(const float4*)(&Bs[cur][kk][cA]);
            *(float4*)(b + 4) = *(const float4*)(&Bs[cur][kk][64 + cA]);
#pragma unroll
            for (int i = 0; i < 10; ++i)
#pragma unroll
                for (int j = 0; j < 8; ++j) acc[i][j] += a[i] * b[j];
        }
        if (c + 1 < NCH) {
            __syncthreads();  // all reads of the buffer we overwrite are done
            const int nxt = cur ^ 1;
#pragma unroll
            for (int j = 0; j < 5; ++j) {
                As[nxt][kp2][aslot[j]]     = xa[j].x;
                As[nxt][kp2 + 1][aslot[j]] = xa[j].y;
            }
            *(float4*)(&Bs[nxt][brow][bcol])     = wb0;
            *(float4*)(&Bs[nxt][brow + 8][bcol]) = wb1;
            __syncthreads();  // writes visible before next compute
        }
    }

    // ---- epilogue: xp write + fused attention dots (coalesced via LDS staging) ----
    __syncthreads();
    float* sE = (float*)As;  // asrc block: floats [0,640); adst block: [640,1280)

    float4 vsl = *(const float4*)(att_src + cA);
    float4 vsh = *(const float4*)(att_src + 64 + cA);
    float4 vdl = *(const float4*)(att_dst + cA);
    float4 vdh = *(const float4*)(att_dst + 64 + cA);
#pragma unroll
    for (int i = 0; i < 10; ++i) {
        const int r = ty * 10 + i;      // local row 0..159
        const int gr = m0 + r;
        float sl = acc[i][0] * vsl.x + acc[i][1] * vsl.y + acc[i][2] * vsl.z + acc[i][3] * vsl.w;
        float sh = acc[i][4] * vsh.x + acc[i][5] * vsh.y + acc[i][6] * vsh.z + acc[i][7] * vsh.w;
        float dl = acc[i][0] * vdl.x + acc[i][1] * vdl.y + acc[i][2] * vdl.z + acc[i][3] * vdl.w;
        float dh = acc[i][4] * vdh.x + acc[i][5] * vdh.y + acc[i][6] * vdh.z + acc[i][7] * vdh.w;
        // reduce over the 8 lanes sharing a head (tx bits 0..2)
        sl += __shfl_xor(sl, 1, 64); sl += __shfl_xor(sl, 2, 64); sl += __shfl_xor(sl, 4, 64);
        sh += __shfl_xor(sh, 1, 64); sh += __shfl_xor(sh, 2, 64); sh += __shfl_xor(sh, 4, 64);
        dl += __shfl_xor(dl, 1, 64); dl += __shfl_xor(dl, 2, 64); dl += __shfl_xor(dl, 4, 64);
        dh += __shfl_xor(dh, 1, 64); dh += __shfl_xor(dh, 2, 64); dh += __shfl_xor(dh, 4, 64);
        if ((tx & 7) == 0) {
            const int hl = tx >> 3;       // 0: heads 0/2, 1: heads 1/3
            sE[r * 4 + hl]           = sl;
            sE[r * 4 + 2 + hl]       = sh;
            sE[640 + r * 4 + hl]     = dl;
            sE[640 + r * 4 + 2 + hl] = dh;
        }
        if (gr < n) {
            *(float4*)(xp + (size_t)gr * HC + cA)      = *(float4*)(&acc[i][0]);
            *(float4*)(xp + (size_t)gr * HC + 64 + cA) = *(float4*)(&acc[i][4]);
        }
    }
    __syncthreads();
    if (tid < 160 && m0 + tid < n) {
        ((float4*)asrc)[m0 + tid] = ((const float4*)sE)[tid];
        cnt[m0 + tid] = 1;
    }
    if (tid >= 96) {
        const int r = tid - 96;          // 0..159
        if (m0 + r < n) ((float4*)adst)[m0 + r] = ((const float4*)sE)[160 + r];
    }
}

// ---------- K_count ----------
__global__ void k_count(const int* __restrict__ ei, int* __restrict__ cnt, int E) {
    int e = blockIdx.x * blockDim.x + threadIdx.x;
    if (e >= E) return;
    atomicAdd(cnt + ei[E + e], 1);
}

// ---------- hierarchical scan: chunk=1024 ----------
// scan1: per-chunk reduce -> bsum[b]
__global__ __launch_bounds__(256) void k_scan1(const int* __restrict__ cnt,
                                               int* __restrict__ bsum, int n) {
    __shared__ int sm[256];
    int b = blockIdx.x, t = threadIdx.x;
    int base = b << 10;
    int s = 0;
#pragma unroll
    for (int j = 0; j < 4; ++j) {
        int i = base + t + j * 256;
        if (i < n) s += cnt[i];
    }
    sm[t] = s;
    __syncthreads();
    for (int d = 128; d > 0; d >>= 1) {
        if (t < d) sm[t] += sm[t + d];
        __syncthreads();
    }
    if (t == 0) bsum[b] = sm[0];
}

// scan2: exclusive scan of bsum (nb <= 1024); also offs[n] = total (known statically)
__global__ __launch_bounds__(1024) void k_scan2(int* __restrict__ bsum,
                                                int* __restrict__ offs,
                                                int nb, int n, int total) {
    __shared__ int sm[1024];
    int t = threadIdx.x;
    int orig = (t < nb) ? bsum[t] : 0;
    sm[t] = orig;
    __syncthreads();
    for (int d = 1; d < 1024; d <<= 1) {
        int v = (t >= d) ? sm[t - d] : 0;
        __syncthreads();
        sm[t] += v;
        __syncthreads();
    }
    if (t < nb) bsum[t] = sm[t] - orig;  // exclusive base per chunk
    if (t == 0) offs[n] = total;
}

// scan3: per-chunk exclusive scan (4 elems/thread) + chunk base -> offs, cursor
__global__ __launch_bounds__(256) void k_scan3(const int* __restrict__ cnt,
                                               const int* __restrict__ bsum,
                                               int* __restrict__ offs,
                                               int* __restrict__ cursor, int n) {
    __shared__ int sm[256];
    int b = blockIdx.x, t = threadIdx.x;
    int base = (b << 10) + t * 4;
    int c[4];
    int s = 0;
#pragma unroll
    for (int j = 0; j < 4; ++j) {
        int i = base + j;
        c[j] = (i < n) ? cnt[i] : 0;
        s += c[j];
    }
    sm[t] = s;
    __syncthreads();
    for (int d = 1; d < 256; d <<= 1) {
        int v = (t >= d) ? sm[t - d] : 0;
        __syncthreads();
        sm[t] += v;
        __syncthreads();
    }
    int excl = bsum[b] + ((t == 0) ? 0 : sm[t - 1]);
#pragma unroll
    for (int j = 0; j < 4; ++j) {
        int i = base + j;
        if (i < n) { offs[i] = excl; cursor[i] = excl; }
        excl += c[j];
    }
}

// ---------- K_fill ----------
__global__ void k_fill(const int* __restrict__ ei, int* __restrict__ cursor,
                       int* __restrict__ srcs, int E, int n) {
    int e = blockIdx.x * blockDim.x + threadIdx.x;
    if (e >= E + n) return;
    int s, d;
    if (e < E) { s = ei[e]; d = ei[E + e]; } else { s = d = e - E; }
    int pos = atomicAdd(cursor + d, 1);
    srcs[pos] = s;
}

// ---------- K_gat: one wave per dst node ----------
// pass 1: softmax stats (srcs staged via LDS).
// pass 2: 4 quarter-waves process 4 edges in parallel (8 in flight),
//         each lane owns 8 channels (2 x float4) -> coalesced 512B row/quarter.
__global__ __launch_bounds__(256) void k_gat(const int* __restrict__ offs,
                                             const int* __restrict__ srcs,
                                             const float* __restrict__ asrc,
                                             const float* __restrict__ adst,
                                             const float* __restrict__ xp,
                                             const float* __restrict__ bias,
                                             float* __restrict__ out, int n) {
    __shared__ int sS[4][128];
    const int wid = threadIdx.x >> 6;
    const int wave = blockIdx.x * 4 + wid;
    if (wave >= n) return;
    const int lane = threadIdx.x & 63;
    const int d = wave;
    const int start = offs[d], end = offs[d + 1];
    const int deg = end - start;

    const int h = lane & 3;
    const float ad_h = adst[(size_t)d * 4 + h];
    float m = -1e30f, Z = 0.f;

    // ---- pass 1: online softmax stats over chunks of <=128 edges ----
    for (int c0 = start; c0 < end; c0 += 128) {
        const int cn = min(128, end - c0);
        if (c0 + lane < end)      sS[wid][lane]      = srcs[c0 + lane];
        if (c0 + 64 + lane < end) sS[wid][64 + lane] = srcs[c0 + 64 + lane];
        asm volatile("s_waitcnt lgkmcnt(0)" ::: "memory");  // intra-wave LDS visibility
        for (int i = (lane >> 2); i < cn; i += 16) {
            int s = sS[wid][i];
            float t = asrc[(size_t)s * 4 + h] + ad_h;
            t = t > 0.f ? t : NEG_SLOPE * t;
            float nm = fmaxf(m, t);
            Z = Z * __expf(m - nm) + __expf(t - nm);
            m = nm;
        }
    }
#pragma unroll
    for (int off = 4; off < 64; off <<= 1) {
        float om = __shfl_xor(m, off, 64);
        float oZ = __shfl_xor(Z, off, 64);
        float nm = fmaxf(m, om);
        Z = Z * __expf(m - nm) + oZ * __expf(om - nm);
        m = nm;
    }

    // ---- pass 2 ----
    const int cl = lane & 15;   // channel lane: channels [cl*8, cl*8+8)
    const int eg = lane >> 4;   // edge slot (4 edges in parallel)
    const int hh = cl >> 2;     // head owning this channel slice
    const float m2  = __shfl(m, hh, 64);
    const float rZ  = 1.0f / __shfl(Z, hh, 64);
    const float ad2 = __shfl(ad_h, hh, 64);

    float4 a0 = make_float4(0.f, 0.f, 0.f, 0.f);
    float4 a1 = make_float4(0.f, 0.f, 0.f, 0.f);

    for (int c0 = start; c0 < end; c0 += 128) {
        const int cn = min(128, end - c0);
        if (deg > 128) {  // multi-chunk fallback: re-stage this chunk
            if (c0 + lane < end)      sS[wid][lane]      = srcs[c0 + lane];
            if (c0 + 64 + lane < end) sS[wid][64 + lane] = srcs[c0 + 64 + lane];
            asm volatile("s_waitcnt lgkmcnt(0)" ::: "memory");
        }
        const int full = cn & ~7;
        int i = 0;
        for (; i < full; i += 8) {  // 8 edges in flight, no guards
            int sa = sS[wid][i + eg];
            int sb = sS[wid][i + 4 + eg];
            float ta = asrc[(size_t)sa * 4 + hh] + ad2;
            float tb = asrc[(size_t)sb * 4 + hh] + ad2;
            const float4* xa = (const float4*)(xp + (size_t)sa * HC + cl * 8);
            const float4* xb = (const float4*)(xp + (size_t)sb * HC + cl * 8);
            float4 va0 = xa[0], va1 = xa[1];
            float4 vb0 = xb[0], vb1 = xb[1];
            ta = ta > 0.f ? ta : NEG_SLOPE * ta;
            tb = tb > 0.f ? tb : NEG_SLOPE * tb;
            float aa = __expf(ta - m2) * rZ;
            float ab = __expf(tb - m2) * rZ;
            a0.x += aa * va0.x; a0.y += aa * va0.y; a0.z += aa * va0.z; a0.w += aa * va0.w;
            a1.x += aa * va1.x; a1.y += aa * va1.y; a1.z += aa * va1.z; a1.w += aa * va1.w;
            a0.x += ab * vb0.x; a0.y += ab * vb0.y; a0.z += ab * vb0.z; a0.w += ab * vb0.w;
            a1.x += ab * vb1.x; a1.y += ab * vb1.y; a1.z += ab * vb1.z; a1.w += ab * vb1.w;
        }
        for (; i < cn; i += 4) {  // tail: exec-masked so no wasted row loads
            if (i + eg < cn) {
                int s = sS[wid][i + eg];
                float t = asrc[(size_t)s * 4 + hh] + ad2;
                const float4* xr = (const float4*)(xp + (size_t)s * HC + cl * 8);
                float4 v0 = xr[0], v1 = xr[1];
                t = t > 0.f ? t : NEG_SLOPE * t;
                float al = __expf(t - m2) * rZ;
                a0.x += al * v0.x; a0.y += al * v0.y; a0.z += al * v0.z; a0.w += al * v0.w;
                a1.x += al * v1.x; a1.y += al * v1.y; a1.z += al * v1.z; a1.w += al * v1.w;
            }
        }
    }

    // reduce across the 4 edge groups (lane bits 4 and 5)
#pragma unroll
    for (int off = 16; off < 64; off <<= 1) {
        a0.x += __shfl_xor(a0.x, off, 64); a0.y += __shfl_xor(a0.y, off, 64);
        a0.z += __shfl_xor(a0.z, off, 64); a0.w += __shfl_xor(a0.w, off, 64);
        a1.x += __shfl_xor(a1.x, off, 64); a1.y += __shfl_xor(a1.y, off, 64);
        a1.z += __shfl_xor(a1.z, off, 64); a1.w += __shfl_xor(a1.w, off, 64);
    }

    if (eg == 0) {
        const float4* bp = (const float4*)bias + cl * 2;
        float4 b0 = bp[0], b1 = bp[1];
        float4 o0, o1;
        o0.x = fmaxf(a0.x + b0.x, 0.f); o0.y = fmaxf(a0.y + b0.y, 0.f);
        o0.z = fmaxf(a0.z + b0.z, 0.f); o0.w = fmaxf(a0.w + b0.w, 0.f);
        o1.x = fmaxf(a1.x + b1.x, 0.f); o1.y = fmaxf(a1.y + b1.y, 0.f);
        o1.z = fmaxf(a1.z + b1.z, 0.f); o1.w = fmaxf(a1.w + b1.w, 0.f);
        float4* op = (float4*)(out + (size_t)d * HC) + cl * 2;
        op[0] = o0; op[1] = o1;
    }
}

extern "C" void kernel_launch(void* const* d_in, const int* in_sizes, int n_in,
                              void* d_out, int out_size, void* d_ws, size_t ws_size,
                              hipStream_t stream) {
    const float* x       = (const float*)d_in[0];
    const int*   ei      = (const int*)d_in[1];
    const float* W       = (const float*)d_in[3];
    const float* att_src = (const float*)d_in[4];
    const float* att_dst = (const float*)d_in[5];
    const float* bias    = (const float*)d_in[6];
    float* out = (float*)d_out;

    const int n = in_sizes[0] / IN_CH;   // 40000
    const int E = in_sizes[1] / 2;       // 640000
    const int EN = E + n;
    const int NB = (n + 1023) >> 10;     // scan chunks

    // workspace layout
    float* xp   = (float*)d_ws;                          // n*128 f32
    float* asrc = xp + (size_t)n * HC;                   // n*4
    float* adst = asrc + (size_t)n * HEADS;              // n*4
    int*   cnt    = (int*)(adst + (size_t)n * HEADS);    // n
    int*   offs   = cnt + n;                             // n+1
    int*   cursor = offs + n + 1;                        // n
    int*   bsum   = cursor + n;                          // NB
    int*   srcs   = bsum + 1024;                         // E+n

    k_gemm<<<dim3((n + BM - 1) / BM), 256, 0, stream>>>(x, W, att_src, att_dst, xp, asrc, adst, cnt, n);
    k_count<<<(E + 255) / 256, 256, 0, stream>>>(ei, cnt, E);
    k_scan1<<<NB, 256, 0, stream>>>(cnt, bsum, n);
    k_scan2<<<1, 1024, 0, stream>>>(bsum, offs, NB, n, EN);
    k_scan3<<<NB, 256, 0, stream>>>(cnt, bsum, offs, cursor, n);
    k_fill<<<(EN + 255) / 256, 256, 0, stream>>>(ei, cursor, srcs, E, n);
    k_gat<<<(n + 3) / 4, 256, 0, stream>>>(offs, srcs, asrc, adst, xp, bias, out, n);
}

// Round 7
// 176.768 us; speedup vs baseline: 1.2225x; 1.0191x over previous
//
#include <hip/hip_runtime.h>
#include <hip/hip_bf16.h>
#include <stdint.h>

#define IN_CH 256
#define HC    128   // HEADS * C
#define HEADS 4
#define CPH   32    // channels per head
#define NEG_SLOPE 0.2f

using f32x4  = __attribute__((ext_vector_type(4))) float;
using bf16x8 = __attribute__((ext_vector_type(8))) short;

// ---------- K_prep: W [256][128] f32 -> W^T hi/lo bf16 [128 cols][256 k] ----------
// Split: hi = trunc-to-bf16(w), lo = trunc-to-bf16(w - hi). One-off, 128 KB output.
__global__ __launch_bounds__(256) void k_prep(const float* __restrict__ W,
                                              unsigned short* __restrict__ wthi,
                                              unsigned short* __restrict__ wtlo) {
    __shared__ unsigned short shh[128][18];  // pad 18: conflict-light b16 scatter
    __shared__ unsigned short shl[128][18];
    const int t = threadIdx.x, b = blockIdx.x;
    const int k0 = b * 16;
#pragma unroll
    for (int j = 0; j < 8; ++j) {
        int idx = t + j * 256;              // 0..2047 over 16k x 128c
        int kk = idx >> 7, c = idx & 127;
        float v = W[(size_t)(k0 + kk) * HC + c];
        unsigned int u = __float_as_uint(v);
        float fl = v - __uint_as_float(u & 0xFFFF0000u);
        shh[c][kk] = (unsigned short)(u >> 16);
        shl[c][kk] = (unsigned short)(__float_as_uint(fl) >> 16);
    }
    __syncthreads();
    const int c = t & 127, seg = t >> 7;    // seg 0/1 -> k halves of 8
    unsigned short tmp[8];
    uint4 o;
#pragma unroll
    for (int i = 0; i < 8; ++i) tmp[i] = shh[c][seg * 8 + i];
    o.x = tmp[0] | ((unsigned int)tmp[1] << 16);
    o.y = tmp[2] | ((unsigned int)tmp[3] << 16);
    o.z = tmp[4] | ((unsigned int)tmp[5] << 16);
    o.w = tmp[6] | ((unsigned int)tmp[7] << 16);
    *(uint4*)(wthi + (size_t)c * IN_CH + k0 + seg * 8) = o;
#pragma unroll
    for (int i = 0; i < 8; ++i) tmp[i] = shl[c][seg * 8 + i];
    o.x = tmp[0] | ((unsigned int)tmp[1] << 16);
    o.y = tmp[2] | ((unsigned int)tmp[3] << 16);
    o.z = tmp[4] | ((unsigned int)tmp[5] << 16);
    o.w = tmp[6] | ((unsigned int)tmp[7] << 16);
    *(uint4*)(wtlo + (size_t)c * IN_CH + k0 + seg * 8) = o;
}

// f32x8 -> bf16 hi/lo frags (truncation split; combined error ~2^-16 rel)
__device__ inline void cvt_hilo(const float4& a, const float4& b, bf16x8& hi, bf16x8& lo) {
    const float f[8] = {a.x, a.y, a.z, a.w, b.x, b.y, b.z, b.w};
#pragma unroll
    for (int e = 0; e < 8; ++e) {
        unsigned int u = __float_as_uint(f[e]);
        hi[e] = (short)(u >> 16);
        float fl = f[e] - __uint_as_float(u & 0xFFFF0000u);
        lo[e] = (short)(__float_as_uint(fl) >> 16);
    }
}

// ---------- K_gemm v7: MFMA bf16x2 split GEMM, xp = x @ W, fused att-dot epilogue ----
// One wave per 32 rows x 128 cols. No LDS, no barriers. acc[2][8] f32x4 (m89 C/D
// layout). A frag: lane row=l&15, k=8*(l>>4)+e (one 16B f32 pair load + cvt);
// B frag: lane col=l&15 from pre-transposed W^T hi/lo (one uint4 = 8 bf16).
// 3 MFMA passes: hi*hi + hi*lo + lo*hi. x streamed (HBM-bound), W^T L2-resident.
__global__ __launch_bounds__(256) void k_gemm(const float* __restrict__ x,
                                              const unsigned short* __restrict__ wthi,
                                              const unsigned short* __restrict__ wtlo,
                                              const float* __restrict__ att_src,
                                              const float* __restrict__ att_dst,
                                              float* __restrict__ xp,
                                              float* __restrict__ asrc,
                                              float* __restrict__ adst,
                                              int* __restrict__ cnt, int n) {
    const int wave = blockIdx.x * 4 + (threadIdx.x >> 6);
    const int m0 = wave * 32;
    if (m0 >= n) return;
    const int l  = threadIdx.x & 63;
    const int lr = l & 15;
    const int q  = l >> 4;
    const int kq = q * 8;   // this lane's k-offset within a 32-k step

    f32x4 acc[2][8];
    const f32x4 zero = {0.f, 0.f, 0.f, 0.f};
#pragma unroll
    for (int i = 0; i < 2; ++i)
#pragma unroll
        for (int j = 0; j < 8; ++j) acc[i][j] = zero;

    const float* ar0 = x + (size_t)(m0 + lr) * IN_CH + kq;
    const float* ar1 = ar0 + 16 * IN_CH;
    const unsigned short* bh = wthi + (size_t)lr * IN_CH + kq;
    const unsigned short* bl = wtlo + (size_t)lr * IN_CH + kq;

    float4 a0l = *(const float4*)(ar0);
    float4 a0h = *(const float4*)(ar0 + 4);
    float4 a1l = *(const float4*)(ar1);
    float4 a1h = *(const float4*)(ar1 + 4);

    for (int kc = 0; kc < IN_CH; kc += 32) {
        bf16x8 a0hi, a0lo, a1hi, a1lo;
        cvt_hilo(a0l, a0h, a0hi, a0lo);
        cvt_hilo(a1l, a1h, a1hi, a1lo);
        if (kc + 32 < IN_CH) {  // register prefetch of next A step (hides HBM latency)
            a0l = *(const float4*)(ar0 + kc + 32);
            a0h = *(const float4*)(ar0 + kc + 36);
            a1l = *(const float4*)(ar1 + kc + 32);
            a1h = *(const float4*)(ar1 + kc + 36);
        }
#pragma unroll
        for (int ct = 0; ct < 8; ++ct) {
            uint4 uh = *(const uint4*)(bh + (size_t)ct * 16 * IN_CH + kc);
            uint4 ul = *(const uint4*)(bl + (size_t)ct * 16 * IN_CH + kc);
            bf16x8 bhi = __builtin_bit_cast(bf16x8, uh);
            bf16x8 blo = __builtin_bit_cast(bf16x8, ul);
            acc[0][ct] = __builtin_amdgcn_mfma_f32_16x16x32_bf16(a0lo, bhi, acc[0][ct], 0, 0, 0);
            acc[0][ct] = __builtin_amdgcn_mfma_f32_16x16x32_bf16(a0hi, blo, acc[0][ct], 0, 0, 0);
            acc[0][ct] = __builtin_amdgcn_mfma_f32_16x16x32_bf16(a0hi, bhi, acc[0][ct], 0, 0, 0);
            acc[1][ct] = __builtin_amdgcn_mfma_f32_16x16x32_bf16(a1lo, bhi, acc[1][ct], 0, 0, 0);
            acc[1][ct] = __builtin_amdgcn_mfma_f32_16x16x32_bf16(a1hi, blo, acc[1][ct], 0, 0, 0);
            acc[1][ct] = __builtin_amdgcn_mfma_f32_16x16x32_bf16(a1hi, bhi, acc[1][ct], 0, 0, 0);
        }
    }

    // ---- fused attention dots: per row, per head, reduce over the 16 col-lanes ----
    float as_c[8], ad_c[8];
#pragma unroll
    for (int ct = 0; ct < 8; ++ct) {
        as_c[ct] = att_src[ct * 16 + lr];
        ad_c[ct] = att_dst[ct * 16 + lr];
    }
#pragma unroll
    for (int rt = 0; rt < 2; ++rt)
#pragma unroll
        for (int h = 0; h < 4; ++h)
#pragma unroll
            for (int r = 0; r < 4; ++r) {
                float s = acc[rt][2 * h][r] * as_c[2 * h] + acc[rt][2 * h + 1][r] * as_c[2 * h + 1];
                float d = acc[rt][2 * h][r] * ad_c[2 * h] + acc[rt][2 * h + 1][r] * ad_c[2 * h + 1];
                s += __shfl_xor(s, 1, 64); s += __shfl_xor(s, 2, 64);
                s += __shfl_xor(s, 4, 64); s += __shfl_xor(s, 8, 64);
                d += __shfl_xor(d, 1, 64); d += __shfl_xor(d, 2, 64);
                d += __shfl_xor(d, 4, 64); d += __shfl_xor(d, 8, 64);
                if (lr == h) {
                    int row = m0 + rt * 16 + q * 4 + r;
                    asrc[(size_t)row * 4 + h] = s;
                    adst[(size_t)row * 4 + h] = d;
                }
            }

    // ---- xp store (m89 C/D layout) + cnt=1 self-loop ----
#pragma unroll
    for (int rt = 0; rt < 2; ++rt)
#pragma unroll
        for (int r = 0; r < 4; ++r) {
            int row = m0 + rt * 16 + q * 4 + r;
            if (lr == 8) cnt[row] = 1;
            float* xr = xp + (size_t)row * HC + lr;
#pragma unroll
            for (int ct = 0; ct < 8; ++ct)
                xr[ct * 16] = acc[rt][ct][r];
        }
}

// ---------- K_count ----------
__global__ void k_count(const int* __restrict__ ei, int* __restrict__ cnt, int E) {
    int e = blockIdx.x * blockDim.x + threadIdx.x;
    if (e >= E) return;
    atomicAdd(cnt + ei[E + e], 1);
}

// ---------- hierarchical scan: chunk=1024 ----------
__global__ __launch_bounds__(256) void k_scan1(const int* __restrict__ cnt,
                                               int* __restrict__ bsum, int n) {
    __shared__ int sm[256];
    int b = blockIdx.x, t = threadIdx.x;
    int base = b << 10;
    int s = 0;
#pragma unroll
    for (int j = 0; j < 4; ++j) {
        int i = base + t + j * 256;
        if (i < n) s += cnt[i];
    }
    sm[t] = s;
    __syncthreads();
    for (int d = 128; d > 0; d >>= 1) {
        if (t < d) sm[t] += sm[t + d];
        __syncthreads();
    }
    if (t == 0) bsum[b] = sm[0];
}

__global__ __launch_bounds__(1024) void k_scan2(int* __restrict__ bsum,
                                                int* __restrict__ offs,
                                                int nb, int n, int total) {
    __shared__ int sm[1024];
    int t = threadIdx.x;
    int orig = (t < nb) ? bsum[t] : 0;
    sm[t] = orig;
    __syncthreads();
    for (int d = 1; d < 1024; d <<= 1) {
        int v = (t >= d) ? sm[t - d] : 0;
        __syncthreads();
        sm[t] += v;
        __syncthreads();
    }
    if (t < nb) bsum[t] = sm[t] - orig;
    if (t == 0) offs[n] = total;
}

__global__ __launch_bounds__(256) void k_scan3(const int* __restrict__ cnt,
                                               const int* __restrict__ bsum,
                                               int* __restrict__ offs,
                                               int* __restrict__ cursor, int n) {
    __shared__ int sm[256];
    int b = blockIdx.x, t = threadIdx.x;
    int base = (b << 10) + t * 4;
    int c[4];
    int s = 0;
#pragma unroll
    for (int j = 0; j < 4; ++j) {
        int i = base + j;
        c[j] = (i < n) ? cnt[i] : 0;
        s += c[j];
    }
    sm[t] = s;
    __syncthreads();
    for (int d = 1; d < 256; d <<= 1) {
        int v = (t >= d) ? sm[t - d] : 0;
        __syncthreads();
        sm[t] += v;
        __syncthreads();
    }
    int excl = bsum[b] + ((t == 0) ? 0 : sm[t - 1]);
#pragma unroll
    for (int j = 0; j < 4; ++j) {
        int i = base + j;
        if (i < n) { offs[i] = excl; cursor[i] = excl; }
        excl += c[j];
    }
}

// ---------- K_fill ----------
__global__ void k_fill(const int* __restrict__ ei, int* __restrict__ cursor,
                       int* __restrict__ srcs, int E, int n) {
    int e = blockIdx.x * blockDim.x + threadIdx.x;
    if (e >= E + n) return;
    int s, d;
    if (e < E) { s = ei[e]; d = ei[E + e]; } else { s = d = e - E; }
    int pos = atomicAdd(cursor + d, 1);
    srcs[pos] = s;
}

// ---------- K_gat: one wave per dst node (unchanged) ----------
__global__ __launch_bounds__(256) void k_gat(const int* __restrict__ offs,
                                             const int* __restrict__ srcs,
                                             const float* __restrict__ asrc,
                                             const float* __restrict__ adst,
                                             const float* __restrict__ xp,
                                             const float* __restrict__ bias,
                                             float* __restrict__ out, int n) {
    __shared__ int sS[4][128];
    const int wid = threadIdx.x >> 6;
    const int wave = blockIdx.x * 4 + wid;
    if (wave >= n) return;
    const int lane = threadIdx.x & 63;
    const int d = wave;
    const int start = offs[d], end = offs[d + 1];
    const int deg = end - start;

    const int h = lane & 3;
    const float ad_h = adst[(size_t)d * 4 + h];
    float m = -1e30f, Z = 0.f;

    for (int c0 = start; c0 < end; c0 += 128) {
        const int cn = min(128, end - c0);
        if (c0 + lane < end)      sS[wid][lane]      = srcs[c0 + lane];
        if (c0 + 64 + lane < end) sS[wid][64 + lane] = srcs[c0 + 64 + lane];
        asm volatile("s_waitcnt lgkmcnt(0)" ::: "memory");
        for (int i = (lane >> 2); i < cn; i += 16) {
            int s = sS[wid][i];
            float t = asrc[(size_t)s * 4 + h] + ad_h;
            t = t > 0.f ? t : NEG_SLOPE * t;
            float nm = fmaxf(m, t);
            Z = Z * __expf(m - nm) + __expf(t - nm);
            m = nm;
        }
    }
#pragma unroll
    for (int off = 4; off < 64; off <<= 1) {
        float om = __shfl_xor(m, off, 64);
        float oZ = __shfl_xor(Z, off, 64);
        float nm = fmaxf(m, om);
        Z = Z * __expf(m - nm) + oZ * __expf(om - nm);
        m = nm;
    }

    const int cl = lane & 15;
    const int eg = lane >> 4;
    const int hh = cl >> 2;
    const float m2  = __shfl(m, hh, 64);
    const float rZ  = 1.0f / __shfl(Z, hh, 64);
    const float ad2 = __shfl(ad_h, hh, 64);

    float4 a0 = make_float4(0.f, 0.f, 0.f, 0.f);
    float4 a1 = make_float4(0.f, 0.f, 0.f, 0.f);

    for (int c0 = start; c0 < end; c0 += 128) {
        const int cn = min(128, end - c0);
        if (deg > 128) {
            if (c0 + lane < end)      sS[wid][lane]      = srcs[c0 + lane];
            if (c0 + 64 + lane < end) sS[wid][64 + lane] = srcs[c0 + 64 + lane];
            asm volatile("s_waitcnt lgkmcnt(0)" ::: "memory");
        }
        const int full = cn & ~7;
        int i = 0;
        for (; i < full; i += 8) {
            int sa = sS[wid][i + eg];
            int sb = sS[wid][i + 4 + eg];
            float ta = asrc[(size_t)sa * 4 + hh] + ad2;
            float tb = asrc[(size_t)sb * 4 + hh] + ad2;
            const float4* xa = (const float4*)(xp + (size_t)sa * HC + cl * 8);
            const float4* xb = (const float4*)(xp + (size_t)sb * HC + cl * 8);
            float4 va0 = xa[0], va1 = xa[1];
            float4 vb0 = xb[0], vb1 = xb[1];
            ta = ta > 0.f ? ta : NEG_SLOPE * ta;
            tb = tb > 0.f ? tb : NEG_SLOPE * tb;
            float aa = __expf(ta - m2) * rZ;
            float ab = __expf(tb - m2) * rZ;
            a0.x += aa * va0.x; a0.y += aa * va0.y; a0.z += aa * va0.z; a0.w += aa * va0.w;
            a1.x += aa * va1.x; a1.y += aa * va1.y; a1.z += aa * va1.z; a1.w += aa * va1.w;
            a0.x += ab * vb0.x; a0.y += ab * vb0.y; a0.z += ab * vb0.z; a0.w += ab * vb0.w;
            a1.x += ab * vb1.x; a1.y += ab * vb1.y; a1.z += ab * vb1.z; a1.w += ab * vb1.w;
        }
        for (; i < cn; i += 4) {
            if (i + eg < cn) {
                int s = sS[wid][i + eg];
                float t = asrc[(size_t)s * 4 + hh] + ad2;
                const float4* xr = (const float4*)(xp + (size_t)s * HC + cl * 8);
                float4 v0 = xr[0], v1 = xr[1];
                t = t > 0.f ? t : NEG_SLOPE * t;
                float al = __expf(t - m2) * rZ;
                a0.x += al * v0.x; a0.y += al * v0.y; a0.z += al * v0.z; a0.w += al * v0.w;
                a1.x += al * v1.x; a1.y += al * v1.y; a1.z += al * v1.z; a1.w += al * v1.w;
            }
        }
    }

#pragma unroll
    for (int off = 16; off < 64; off <<= 1) {
        a0.x += __shfl_xor(a0.x, off, 64); a0.y += __shfl_xor(a0.y, off, 64);
        a0.z += __shfl_xor(a0.z, off, 64); a0.w += __shfl_xor(a0.w, off, 64);
        a1.x += __shfl_xor(a1.x, off, 64); a1.y += __shfl_xor(a1.y, off, 64);
        a1.z += __shfl_xor(a1.z, off, 64); a1.w += __shfl_xor(a1.w, off, 64);
    }

    if (eg == 0) {
        const float4* bp = (const float4*)bias + cl * 2;
        float4 b0 = bp[0], b1 = bp[1];
        float4 o0, o1;
        o0.x = fmaxf(a0.x + b0.x, 0.f); o0.y = fmaxf(a0.y + b0.y, 0.f);
        o0.z = fmaxf(a0.z + b0.z, 0.f); o0.w = fmaxf(a0.w + b0.w, 0.f);
        o1.x = fmaxf(a1.x + b1.x, 0.f); o1.y = fmaxf(a1.y + b1.y, 0.f);
        o1.z = fmaxf(a1.z + b1.z, 0.f); o1.w = fmaxf(a1.w + b1.w, 0.f);
        float4* op = (float4*)(out + (size_t)d * HC) + cl * 2;
        op[0] = o0; op[1] = o1;
    }
}

extern "C" void kernel_launch(void* const* d_in, const int* in_sizes, int n_in,
                              void* d_out, int out_size, void* d_ws, size_t ws_size,
                              hipStream_t stream) {
    const float* x       = (const float*)d_in[0];
    const int*   ei      = (const int*)d_in[1];
    const float* W       = (const float*)d_in[3];
    const float* att_src = (const float*)d_in[4];
    const float* att_dst = (const float*)d_in[5];
    const float* bias    = (const float*)d_in[6];
    float* out = (float*)d_out;

    const int n = in_sizes[0] / IN_CH;   // 40000
    const int E = in_sizes[1] / 2;       // 640000
    const int EN = E + n;
    const int NB = (n + 1023) >> 10;     // scan chunks

    // workspace layout
    float* xp   = (float*)d_ws;                          // n*128 f32
    float* asrc = xp + (size_t)n * HC;                   // n*4
    float* adst = asrc + (size_t)n * HEADS;              // n*4
    int*   cnt    = (int*)(adst + (size_t)n * HEADS);    // n
    int*   offs   = cnt + n;                             // n+1
    int*   cursor = offs + n + 1;                        // n
    int*   bsum   = cursor + n;                          // NB
    int*   srcs   = bsum + 1024;                         // E+n
    unsigned short* wthi = (unsigned short*)(((uintptr_t)(srcs + EN) + 63) & ~(uintptr_t)63);
    unsigned short* wtlo = wthi + (size_t)HC * IN_CH;    // 64 KB each

    k_prep<<<16, 256, 0, stream>>>(W, wthi, wtlo);
    {
        const int nwaves = (n + 31) / 32;
        k_gemm<<<(nwaves + 3) / 4, 256, 0, stream>>>(x, wthi, wtlo, att_src, att_dst,
                                                     xp, asrc, adst, cnt, n);
    }
    k_count<<<(E + 255) / 256, 256, 0, stream>>>(ei, cnt, E);
    k_scan1<<<NB, 256, 0, stream>>>(cnt, bsum, n);
    k_scan2<<<1, 1024, 0, stream>>>(bsum, offs, NB, n, EN);
    k_scan3<<<NB, 256, 0, stream>>>(cnt, bsum, offs, cursor, n);
    k_fill<<<(EN + 255) / 256, 256, 0, stream>>>(ei, cursor, srcs, E, n);
    k_gat<<<(n + 3) / 4, 256, 0, stream>>>(offs, srcs, asrc, adst, xp, bias, out, n);
}